// Round 5
// baseline (130.989 us; speedup 1.0000x reference)
//
#include <hip/hip_runtime.h>

// SharedGroupLinearLayer R5.
// R2-R4 post-mortem: three different per-wave register pipelines all plateau
// at 2.4-2.6 TB/s with ~8 waves/CU. fillBuffer hits 6.5 TB/s with 8 VGPR +
// huge TLP; copy ubench needs 5 B/cy/CU read with 32 waves/CU. Lever is
// resident wave count, not per-wave depth. This round: 512-thr blocks x 1024
// = all 8192 waves resident (4 blocks/CU), VGPR<=64 (8 waves/SIMD), 2 tiles
// per wave, one pinned 2KB burst per wave. ALL loop-invariants (W frags,
// R frags, acc-init) live in LDS tables.
//
// out[n,o] = (X w1^T + b1) + att0 * (X (w0-w1)^T + (b0-b1)),
// att0 = sigmoid(l0-l1); emb folded into acc init: C0 = b + E·W^T.

#define NBLK 1024   // x 8 waves x 2 tiles x 16 tokens = 262144

typedef short bf16x8 __attribute__((ext_vector_type(8)));
typedef float f32x4  __attribute__((ext_vector_type(4)));

union B8 { bf16x8 v; unsigned u[4]; };

__device__ __forceinline__ unsigned pk2bf(float lo, float hi) {
    unsigned a = __float_as_uint(lo) + 0x8000u;
    unsigned b = __float_as_uint(hi) + 0x8000u;
    return __builtin_amdgcn_perm(b, a, 0x07060302u);
}

__device__ __forceinline__ void pack8(B8& d, float4 p, float4 q) {
    d.u[0] = pk2bf(p.x, p.y); d.u[1] = pk2bf(p.z, p.w);
    d.u[2] = pk2bf(q.x, q.y); d.u[3] = pk2bf(q.z, q.w);
}

__global__ __launch_bounds__(512, 8) void sgll_kernel(
    const float* __restrict__ x,    // (262144, 64)
    const float* __restrict__ emb,  // (16, 64)  row = token % 16
    const float* __restrict__ rw,   // (64, 2)
    const float* __restrict__ ws,   // (2, 64, 64) w_stack[t][o][d]
    const float* __restrict__ bs,   // (2, 64)
    float* __restrict__ out)        // (262144, 64)
{
    __shared__ bf16x8 sW1[8][64];   // [kt*4+ot][lane]  w1 A-frags
    __shared__ bf16x8 sWd[8][64];   // w0-w1 A-frags
    __shared__ bf16x8 sR0[64], sR1[64];  // read_w A-frags
    __shared__ f32x4  sI1[4][64];   // acc init: b1 + E·w1^T
    __shared__ f32x4  sId[4][64];   // db + E·dw^T
    __shared__ f32x4  sIl[64];      // logit init: E·R

    const int tid  = threadIdx.x;
    const int lane = tid & 63;
    const int wv   = tid >> 6;      // 0..7
    const int col  = lane & 15;
    const int q    = lane >> 4;

    // ---- setup: wave wv stages W combo wv (kt = wv>>2, ot = wv&3) ----
    {
        const int kt = wv >> 2, ot = wv & 3;
        const float* p0 = ws + (ot * 16 + col) * 64 + kt * 32 + q * 8;  // w0
        const float* p1 = p0 + 4096;                                    // w1
        float4 a0 = *(const float4*)p0, a1 = *(const float4*)(p0 + 4);
        float4 c0 = *(const float4*)p1, c1 = *(const float4*)(p1 + 4);
        B8 f1, fd;
        pack8(f1, c0, c1);
        fd.u[0] = pk2bf(a0.x - c0.x, a0.y - c0.y);
        fd.u[1] = pk2bf(a0.z - c0.z, a0.w - c0.w);
        fd.u[2] = pk2bf(a1.x - c1.x, a1.y - c1.y);
        fd.u[3] = pk2bf(a1.z - c1.z, a1.w - c1.w);
        sW1[wv][lane] = f1.v;
        sWd[wv][lane] = fd.v;
    }

    // ---- wave 1: R frags -> LDS ----
    if (wv == 1) {
        float v[8];
        B8 r;
        #pragma unroll
        for (int j = 0; j < 8; ++j)
            v[j] = (col < 2) ? rw[(q * 8 + j) * 2 + col] : 0.f;
        pack8(r, make_float4(v[0], v[1], v[2], v[3]), make_float4(v[4], v[5], v[6], v[7]));
        sR0[lane] = r.v;
        #pragma unroll
        for (int j = 0; j < 8; ++j)
            v[j] = (col < 2) ? rw[(32 + q * 8 + j) * 2 + col] : 0.f;
        pack8(r, make_float4(v[0], v[1], v[2], v[3]), make_float4(v[4], v[5], v[6], v[7]));
        sR1[lane] = r.v;
    }

    __syncthreads();   // W + R tables ready

    // ---- wave 0: init tables  C0 = b + E·W^T,  Il = E·R ----
    if (wv == 0) {
        B8 E0, E1;
        const float* ep = emb + col * 64 + q * 8;
        pack8(E0, *(const float4*)ep, *(const float4*)(ep + 4));
        pack8(E1, *(const float4*)(ep + 32), *(const float4*)(ep + 36));
        #pragma unroll
        for (int ot = 0; ot < 4; ++ot) {
            float4 b1 = *(const float4*)(bs + 64 + ot * 16 + q * 4);
            float4 b0 = *(const float4*)(bs + ot * 16 + q * 4);
            f32x4 a1 = {b1.x, b1.y, b1.z, b1.w};
            f32x4 ad = {b0.x - b1.x, b0.y - b1.y, b0.z - b1.z, b0.w - b1.w};
            a1 = __builtin_amdgcn_mfma_f32_16x16x32_bf16(sW1[ot][lane],     E0.v, a1, 0, 0, 0);
            a1 = __builtin_amdgcn_mfma_f32_16x16x32_bf16(sW1[4 + ot][lane], E1.v, a1, 0, 0, 0);
            ad = __builtin_amdgcn_mfma_f32_16x16x32_bf16(sWd[ot][lane],     E0.v, ad, 0, 0, 0);
            ad = __builtin_amdgcn_mfma_f32_16x16x32_bf16(sWd[4 + ot][lane], E1.v, ad, 0, 0, 0);
            sI1[ot][lane] = a1;
            sId[ot][lane] = ad;
        }
        f32x4 z = {0.f, 0.f, 0.f, 0.f};
        z = __builtin_amdgcn_mfma_f32_16x16x32_bf16(sR0[lane], E0.v, z, 0, 0, 0);
        z = __builtin_amdgcn_mfma_f32_16x16x32_bf16(sR1[lane], E1.v, z, 0, 0, 0);
        sIl[lane] = z;
    }
    __syncthreads();   // init tables ready

    // ---- streaming: one pinned 2KB burst (2 tiles), then consume ----
    const long base = (long)(blockIdx.x * 8 + wv) * 32;   // first token
    float4 buf[2][4];
    #pragma unroll
    for (int t = 0; t < 2; ++t) {
        const float* p = x + (base + (long)t * 16 + col) * 64 + q * 8;
        buf[t][0] = *(const float4*)p;        buf[t][1] = *(const float4*)(p + 4);
        buf[t][2] = *(const float4*)(p + 32); buf[t][3] = *(const float4*)(p + 36);
    }
    __builtin_amdgcn_sched_barrier(0);   // keep the burst ahead of compute

    #pragma unroll
    for (int i = 0; i < 2; ++i) {
        B8 X0, X1;
        pack8(X0, buf[i][0], buf[i][1]);
        pack8(X1, buf[i][2], buf[i][3]);

        f32x4 lac = sIl[lane];
        lac = __builtin_amdgcn_mfma_f32_16x16x32_bf16(sR0[lane], X0.v, lac, 0, 0, 0);
        lac = __builtin_amdgcn_mfma_f32_16x16x32_bf16(sR1[lane], X1.v, lac, 0, 0, 0);
        float att = 1.0f / (1.0f + __expf(lac[1] - lac[0]));  // valid on q=0 lanes
        att = __shfl(att, col);                               // broadcast per token

        const long rowoff = (base + (long)i * 16 + col) * 64;
        #pragma unroll
        for (int ot = 0; ot < 4; ++ot) {
            f32x4 y = sI1[ot][lane];
            y = __builtin_amdgcn_mfma_f32_16x16x32_bf16(sW1[ot][lane],     X0.v, y, 0, 0, 0);
            y = __builtin_amdgcn_mfma_f32_16x16x32_bf16(sW1[4 + ot][lane], X1.v, y, 0, 0, 0);
            f32x4 d = sId[ot][lane];
            d = __builtin_amdgcn_mfma_f32_16x16x32_bf16(sWd[ot][lane],     X0.v, d, 0, 0, 0);
            d = __builtin_amdgcn_mfma_f32_16x16x32_bf16(sWd[4 + ot][lane], X1.v, d, 0, 0, 0);
            float4 o;
            o.x = fmaf(att, d[0], y[0]);
            o.y = fmaf(att, d[1], y[1]);
            o.z = fmaf(att, d[2], y[2]);
            o.w = fmaf(att, d[3], y[3]);
            *(float4*)(out + rowoff + ot * 16 + q * 4) = o;   // 16B coalesced
        }
    }
}

extern "C" void kernel_launch(void* const* d_in, const int* in_sizes, int n_in,
                              void* d_out, int out_size, void* d_ws, size_t ws_size,
                              hipStream_t stream) {
    const float* x   = (const float*)d_in[0];
    const float* emb = (const float*)d_in[1];
    const float* rw  = (const float*)d_in[2];
    const float* wsk = (const float*)d_in[3];
    const float* bs  = (const float*)d_in[4];
    float* out = (float*)d_out;
    sgll_kernel<<<NBLK, 512, 0, stream>>>(x, emb, rw, wsk, bs, out);
}